// Round 10
// baseline (270.557 us; speedup 1.0000x reference)
//
#include <hip/hip_runtime.h>
#include <hip/hip_bf16.h>

#define N_NODES 16384
#define E_EDGES 131072
#define F_IN 6
#define S_DIM 4
#define G_GRAPHS 256
#define H_DIM 30
#define C1 32
#define C2 64
#define C3 32

typedef __attribute__((ext_vector_type(8))) short bf16x8;
typedef __attribute__((ext_vector_type(4))) float f32x4;

__device__ __forceinline__ short f2bf(float f) {
    union { float f; unsigned u; } a; a.f = f;
    unsigned r = a.u + 0x7FFFu + ((a.u >> 16) & 1u);
    return (short)(r >> 16);
}

// pack two f32 -> (bf16(a) low16, bf16(b) high16)
__device__ __forceinline__ unsigned pack2(float a, float b) {
    unsigned ua = __float_as_uint(a) + 0x8000u;
    unsigned ub = __float_as_uint(b) + 0x8000u;
    return __builtin_amdgcn_perm(ub, ua, 0x07060302u);
}

// ---------------------------------------------------------------------------
// prep: build wbt1/wbt2 + degree histogram (deg pre-zeroed by memset).
// ---------------------------------------------------------------------------
__global__ __launch_bounds__(256) void prep(
    const float* __restrict__ wk2, const float* __restrict__ bk2,
    const float* __restrict__ wk1, const float* __restrict__ bk1,
    const int* __restrict__ tgt,
    short* __restrict__ wbt2, short* __restrict__ wbt1,
    int* __restrict__ deg)
{
    const int gtid = blockIdx.x * 256 + threadIdx.x;
    if (gtid < 65536) {
        const int idx = gtid;
        const int j = idx & 7, kq = (idx >> 3) & 3, n = (idx >> 5) & 15;
        const int nt = (idx >> 9) & 3, kc = idx >> 11;
        const int c1 = kq * 8 + j, c2 = nt * 16 + n;
        float v = (kc < 30) ? wk2[kc * 2048 + c1 * 64 + c2]
                            : ((kc == 30) ? bk2[c1 * 64 + c2] : 0.f);
        wbt2[idx] = f2bf(v);
    } else if (gtid < 73728) {
        const int i2 = gtid - 65536;
        const int j = i2 & 7, kq = (i2 >> 3) & 3, n = (i2 >> 5) & 15;
        const int nt = (i2 >> 9) & 1, kc = i2 >> 10;
        const int h = kc * 4 + kq, c1 = nt * 16 + n;
        float v = 0.f;
        if (j < 6) {
            if (h < 30) v = wk1[h * 192 + j * 32 + c1];
            else if (h == 30) v = bk1[j * 32 + c1];
        }
        wbt1[i2] = f2bf(v);
    }
    atomicAdd(&deg[tgt[gtid]], 1);
}

// single block, 1024 threads, 16 elems/thread exclusive scan over N=16384
__global__ __launch_bounds__(1024) void csr_scan(
    const int* __restrict__ deg, int* __restrict__ off, int* __restrict__ cursor)
{
    __shared__ int s[1024];
    const int t = threadIdx.x;
    const int base = t * 16;
    int loc[16]; int sum = 0;
    #pragma unroll
    for (int i = 0; i < 16; ++i) { loc[i] = sum; sum += deg[base + i]; }
    s[t] = sum;
    __syncthreads();
    int v = sum;
    for (int d = 1; d < 1024; d <<= 1) {
        const int add = (t >= d) ? s[t - d] : 0;
        __syncthreads();
        v += add; s[t] = v;
        __syncthreads();
    }
    const int pre = v - sum;
    #pragma unroll
    for (int i = 0; i < 16; ++i) {
        const int o = pre + loc[i];
        off[base + i] = o; cursor[base + i] = o;
    }
    if (t == 1023) off[N_NODES] = E_EDGES;
}

// ---------------------------------------------------------------------------
// ECC1 + fused CSR permute + BOTH edge-MLPs (scalar-operand weights from
// global — all weight indices wave-uniform, compiler emits s_load).
// 256 edges/block, 1 thread/edge. Writes msg1 (permuted), h2buf (permuted),
// srcp/gwp (CSR-ordered).
// ---------------------------------------------------------------------------
__global__ __launch_bounds__(256, 2) void ecc1_mfma(
    const float* __restrict__ x, const float* __restrict__ e,
    const int* __restrict__ src, const int* __restrict__ tgt,
    const float* __restrict__ gcn_w,
    const float* __restrict__ w0a, const float* __restrict__ b0a,
    const float* __restrict__ w1a, const float* __restrict__ b1a,
    const float* __restrict__ w0b, const float* __restrict__ b0b,
    const float* __restrict__ w1b, const float* __restrict__ b1b,
    const short* __restrict__ wbt1,
    int* __restrict__ cursor, int* __restrict__ srcp, float* __restrict__ gwp,
    unsigned* __restrict__ msg1, unsigned* __restrict__ h2buf)
{
    __shared__ unsigned short s_h1b[256 * 40];
    __shared__ unsigned short s_xb[256 * 8];
    __shared__ int s_perm[256];

    const int t = threadIdx.x;
    const int tile = blockIdx.x * 256;

    // ---- phase A: permute + x stage + MLP1 + MLP2 (scalar weights) ----
    {
        const int eid = tile + t;
        const int sv = src[eid];
        const int p = atomicAdd(&cursor[tgt[eid]], 1);
        s_perm[t] = p;
        srcp[p] = sv;
        gwp[p] = gcn_w[eid];

        const float2* xp = (const float2*)(x + (size_t)sv * F_IN);
        const float2 a = xp[0], b2 = xp[1], c2 = xp[2];
        *(uint4*)&s_xb[t * 8] =
            make_uint4(pack2(a.x, a.y), pack2(b2.x, b2.y), pack2(c2.x, c2.y), 0u);

        const float4 ev = *(const float4*)(e + eid * 4);

        // ---- MLP 1 (ecc1) -> s_h1b ----
        {
            float h0[30];
            #pragma unroll
            for (int j = 0; j < 30; ++j) {
                float v = ev.x * w0a[j] + ev.y * w0a[30 + j]
                        + ev.z * w0a[60 + j] + ev.w * w0a[90 + j] + b0a[j];
                h0[j] = fmaxf(v, 0.f);
            }
            unsigned hw[16];
            #pragma unroll
            for (int i = 0; i < 15; ++i) {
                float va = b1a[2 * i], vb = b1a[2 * i + 1];
                #pragma unroll
                for (int k = 0; k < 30; ++k) {
                    va += h0[k] * w1a[k * 30 + 2 * i];
                    vb += h0[k] * w1a[k * 30 + 2 * i + 1];
                }
                hw[i] = pack2(fmaxf(va, 0.f), fmaxf(vb, 0.f));
            }
            hw[15] = pack2(1.0f, 0.f);
            uint4* hb = (uint4*)&s_h1b[t * 40];
            hb[0] = make_uint4(hw[0], hw[1], hw[2], hw[3]);
            hb[1] = make_uint4(hw[4], hw[5], hw[6], hw[7]);
            hb[2] = make_uint4(hw[8], hw[9], hw[10], hw[11]);
            hb[3] = make_uint4(hw[12], hw[13], hw[14], hw[15]);
        }
        // ---- MLP 2 (for ecc2) -> h2buf at permuted slot ----
        {
            float h0[30];
            #pragma unroll
            for (int j = 0; j < 30; ++j) {
                float v = ev.x * w0b[j] + ev.y * w0b[30 + j]
                        + ev.z * w0b[60 + j] + ev.w * w0b[90 + j] + b0b[j];
                h0[j] = fmaxf(v, 0.f);
            }
            unsigned hw[16];
            #pragma unroll
            for (int i = 0; i < 15; ++i) {
                float va = b1b[2 * i], vb = b1b[2 * i + 1];
                #pragma unroll
                for (int k = 0; k < 30; ++k) {
                    va += h0[k] * w1b[k * 30 + 2 * i];
                    vb += h0[k] * w1b[k * 30 + 2 * i + 1];
                }
                hw[i] = pack2(fmaxf(va, 0.f), fmaxf(vb, 0.f));
            }
            hw[15] = pack2(1.0f, 0.f);
            uint4* hb2 = (uint4*)h2buf + (size_t)p * 4;
            hb2[0] = make_uint4(hw[0], hw[1], hw[2], hw[3]);
            hb2[1] = make_uint4(hw[4], hw[5], hw[6], hw[7]);
            hb2[2] = make_uint4(hw[8], hw[9], hw[10], hw[11]);
            hb2[3] = make_uint4(hw[12], hw[13], hw[14], hw[15]);
        }
    }
    __syncthreads();

    // ---- MFMA: 4 waves x 4 m-tiles x 2 n-tiles ----
    const int wv = t >> 6, lane = t & 63;
    const int n = lane & 15, quad = lane >> 4;
    const int e0 = wv * 64;

    float xf[4][8];
    #pragma unroll
    for (int m = 0; m < 4; ++m) {
        const uint4 xv = *(const uint4*)&s_xb[(e0 + m * 16 + n) * 8];
        xf[m][0] = __uint_as_float(xv.x << 16);
        xf[m][1] = __uint_as_float(xv.x & 0xFFFF0000u);
        xf[m][2] = __uint_as_float(xv.y << 16);
        xf[m][3] = __uint_as_float(xv.y & 0xFFFF0000u);
        xf[m][4] = __uint_as_float(xv.z << 16);
        xf[m][5] = __uint_as_float(xv.z & 0xFFFF0000u);
        xf[m][6] = 0.f; xf[m][7] = 0.f;
    }

    f32x4 acc[4][2];
    #pragma unroll
    for (int m = 0; m < 4; ++m) {
        acc[m][0] = (f32x4){0.f, 0.f, 0.f, 0.f};
        acc[m][1] = (f32x4){0.f, 0.f, 0.f, 0.f};
    }

    #pragma unroll
    for (int kc = 0; kc < 8; ++kc) {
        bf16x8 bfr[2];
        #pragma unroll
        for (int nt = 0; nt < 2; ++nt)
            bfr[nt] = *(const bf16x8*)(wbt1 + (((kc * 2 + nt) * 16 + n) << 5) + quad * 8);
        #pragma unroll
        for (int m = 0; m < 4; ++m) {
            const unsigned hv = s_h1b[(e0 + m * 16 + n) * 40 + kc * 4 + quad];
            const float hfv = __uint_as_float(hv << 16);
            union { unsigned u[4]; bf16x8 v; } af;
            #pragma unroll
            for (int i = 0; i < 4; ++i)
                af.u[i] = pack2(hfv * xf[m][2 * i], hfv * xf[m][2 * i + 1]);
            acc[m][0] = __builtin_amdgcn_mfma_f32_16x16x32_bf16(af.v, bfr[0], acc[m][0], 0, 0, 0);
            acc[m][1] = __builtin_amdgcn_mfma_f32_16x16x32_bf16(af.v, bfr[1], acc[m][1], 0, 0, 0);
        }
    }

    #pragma unroll
    for (int m = 0; m < 4; ++m)
        #pragma unroll
        for (int r = 0; r < 4; ++r) {
            const int p = s_perm[e0 + m * 16 + quad * 4 + r];
            msg1[p * 16 + n] = pack2(acc[m][0][r], acc[m][1][r]);
        }
}

// gather msg1 (sequential, permuted layout) + node update 1 -> x1
__global__ __launch_bounds__(256) void gather1(
    const unsigned* __restrict__ msg1, const int* __restrict__ off,
    const float* __restrict__ x,
    const float* __restrict__ root, const float* __restrict__ bias,
    float* __restrict__ x1)
{
    __shared__ float s_root[192];
    __shared__ float s_b[32];
    const int t = threadIdx.x;
    if (t < 192) s_root[t] = root[t];
    if (t < 32) s_b[t] = bias[t];
    __syncthreads();
    const int v = blockIdx.x * 16 + (t >> 4);
    const int n = t & 15;
    const int o0 = off[v], o1 = off[v + 1];
    float sa = 0.f, sb = 0.f;
    for (int j = o0; j < o1; ++j) {
        const unsigned u = msg1[j * 16 + n];
        sa += __uint_as_float(u << 16);
        sb += __uint_as_float(u & 0xFFFF0000u);
    }
    const float* xr = x + (size_t)v * F_IN;
    float ra = s_b[n], rb = s_b[16 + n];
    #pragma unroll
    for (int f = 0; f < 6; ++f) {
        const float xv = xr[f];
        ra += xv * s_root[f * 32 + n];
        rb += xv * s_root[f * 32 + 16 + n];
    }
    x1[v * 32 + n] = fmaxf(sa + ra, 0.f);
    x1[v * 32 + 16 + n] = fmaxf(sb + rb, 0.f);
}

// ---------------------------------------------------------------------------
// ECC2: pure MFMA GEMM over CSR-permuted edges (no MLP, no e-loads).
// ---------------------------------------------------------------------------
__global__ __launch_bounds__(256, 6) void ecc2_mfma(
    const float* __restrict__ x1, const int* __restrict__ srcp,
    const unsigned* __restrict__ h2buf,
    const short* __restrict__ wbt2, unsigned* __restrict__ msg2)
{
    __shared__ unsigned short s_h1b[128 * 40];
    __shared__ unsigned short s_x1b[128 * 40];

    const int t = threadIdx.x;
    const int tile = blockIdx.x * 128;
    const int el = t & 127, hf = t >> 7;

    // ---- phase A: stage h1_2 (coalesced) + x1[srcp] (random) ----
    {
        const int p = tile + el;
        const uint4* h2p = (const uint4*)h2buf + (size_t)p * 4 + hf * 2;
        const uint4 a0 = h2p[0], a1 = h2p[1];
        *(uint4*)&s_h1b[el * 40 + hf * 16] = a0;
        *(uint4*)&s_h1b[el * 40 + hf * 16 + 8] = a1;

        const float* xp = x1 + (size_t)srcp[p] * C1 + hf * 16;
        uint4* xb = (uint4*)&s_x1b[el * 40];
        #pragma unroll
        for (int q = 0; q < 2; ++q) {
            const float4 v0 = *(const float4*)(xp + q * 8);
            const float4 v1 = *(const float4*)(xp + q * 8 + 4);
            xb[hf * 2 + q] = make_uint4(pack2(v0.x, v0.y), pack2(v0.z, v0.w),
                                        pack2(v1.x, v1.y), pack2(v1.z, v1.w));
        }
    }
    __syncthreads();

    // ---- MFMA: 4 waves x 2 m-tiles x 4 n-tiles ----
    const int wv = t >> 6, lane = t & 63;
    const int n = lane & 15, quad = lane >> 4;
    const int e0 = wv * 32;

    float xf[2][8];
    #pragma unroll
    for (int m = 0; m < 2; ++m) {
        const uint4 xv = *(const uint4*)&s_x1b[(e0 + m * 16 + n) * 40 + quad * 8];
        xf[m][0] = __uint_as_float(xv.x << 16);
        xf[m][1] = __uint_as_float(xv.x & 0xFFFF0000u);
        xf[m][2] = __uint_as_float(xv.y << 16);
        xf[m][3] = __uint_as_float(xv.y & 0xFFFF0000u);
        xf[m][4] = __uint_as_float(xv.z << 16);
        xf[m][5] = __uint_as_float(xv.z & 0xFFFF0000u);
        xf[m][6] = __uint_as_float(xv.w << 16);
        xf[m][7] = __uint_as_float(xv.w & 0xFFFF0000u);
    }

    f32x4 acc[2][4];
    #pragma unroll
    for (int m = 0; m < 2; ++m)
        #pragma unroll
        for (int nt = 0; nt < 4; ++nt) acc[m][nt] = (f32x4){0.f, 0.f, 0.f, 0.f};

    #pragma unroll 4
    for (int kc = 0; kc < 32; ++kc) {
        bf16x8 bfr[4];
        #pragma unroll
        for (int nt = 0; nt < 4; ++nt)
            bfr[nt] = *(const bf16x8*)(wbt2 + (((kc * 4 + nt) * 16 + n) << 5) + quad * 8);
        #pragma unroll
        for (int m = 0; m < 2; ++m) {
            const unsigned hv = s_h1b[(e0 + m * 16 + n) * 40 + kc];
            const float hfv = __uint_as_float(hv << 16);
            union { unsigned u[4]; bf16x8 v; } af;
            #pragma unroll
            for (int i = 0; i < 4; ++i)
                af.u[i] = pack2(hfv * xf[m][2 * i], hfv * xf[m][2 * i + 1]);
            #pragma unroll
            for (int nt = 0; nt < 4; ++nt)
                acc[m][nt] = __builtin_amdgcn_mfma_f32_16x16x32_bf16(af.v, bfr[nt], acc[m][nt], 0, 0, 0);
        }
    }

    #pragma unroll
    for (int m = 0; m < 2; ++m)
        #pragma unroll
        for (int r = 0; r < 4; ++r) {
            const int p = tile + e0 + m * 16 + quad * 4 + r;
            uint2 val;
            val.x = pack2(acc[m][0][r], acc[m][1][r]);
            val.y = pack2(acc[m][2][r], acc[m][3][r]);
            *(uint2*)&msg2[p * 32 + n * 2] = val;
        }
}

// gather msg2 (sequential) + node update 2 + xw = x2 @ gcn_W -> xw.
// 32 nodes/block: weights staged once, reused 4x.
__global__ __launch_bounds__(256) void gather2(
    const unsigned* __restrict__ msg2, const int* __restrict__ off,
    const float* __restrict__ x1,
    const float* __restrict__ root, const float* __restrict__ bias,
    const float* __restrict__ W, float* __restrict__ xw)
{
    __shared__ float s_root[2048], s_W[2048], s_b[64];
    __shared__ float s_x2[8][68];
    __shared__ float s_x1v[256];
    const int t = threadIdx.x;
    const int nb = blockIdx.x * 32;
    for (int i = t; i < 2048; i += 256) { s_root[i] = root[i]; s_W[i] = W[i]; }
    if (t < 64) s_b[t] = bias[t];

    const int lv = t >> 5;
    const int j5 = t & 31;
    const int n = j5 >> 1, p = j5 & 1;
    const int ca = p * 32 + n, cb = p * 32 + 16 + n;

    #pragma unroll 1
    for (int rd = 0; rd < 4; ++rd) {
        s_x1v[t] = x1[(nb + rd * 8) * 32 + t];
        __syncthreads();
        const int v = nb + rd * 8 + lv;
        const int o0 = off[v], o1 = off[v + 1];
        float sa = 0.f, sb = 0.f;
        for (int j = o0; j < o1; ++j) {
            const unsigned u = msg2[j * 32 + j5];
            sa += __uint_as_float(u << 16);
            sb += __uint_as_float(u & 0xFFFF0000u);
        }
        float ra = s_b[ca], rb = s_b[cb];
        #pragma unroll 8
        for (int k = 0; k < 32; ++k) {
            const float xv = s_x1v[lv * 32 + k];
            ra += xv * s_root[k * 64 + ca];
            rb += xv * s_root[k * 64 + cb];
        }
        s_x2[lv][ca] = fmaxf(sa + ra, 0.f);
        s_x2[lv][cb] = fmaxf(sb + rb, 0.f);
        __syncthreads();
        float av = 0.f;
        #pragma unroll 8
        for (int k = 0; k < 64; ++k) av += s_x2[lv][k] * s_W[k * 32 + j5];
        xw[v * 32 + j5] = av;
    }
}

// GCN gather (CSR-ordered srcp/gwp, sequential) + relu + global pool
__global__ __launch_bounds__(256) void gcn_pool(
    const float* __restrict__ xw, const int* __restrict__ off,
    const int* __restrict__ srcp, const float* __restrict__ gwp,
    const float* __restrict__ gw, const float* __restrict__ gb,
    const int* __restrict__ seg, float* __restrict__ out)
{
    __shared__ float s_gb[32];
    const int t = threadIdx.x;
    if (t < 32) s_gb[t] = gb[t];
    __syncthreads();
    const int v = blockIdx.x * 8 + (t >> 5);
    const int c = t & 31;
    const int o0 = off[v], o1 = off[v + 1];
    float s = gw[E_EDGES + v] * xw[v * 32 + c];   // self loop
    for (int j = o0; j < o1; ++j)
        s += gwp[j] * xw[srcp[j] * 32 + c];
    const float val = fmaxf(s + s_gb[c], 0.f);
    atomicAdd(&out[seg[v] * 32 + c], val);
}

extern "C" void kernel_launch(void* const* d_in, const int* in_sizes, int n_in,
                              void* d_out, int out_size, void* d_ws, size_t ws_size,
                              hipStream_t stream)
{
    const float* x       = (const float*)d_in[0];
    const float* e       = (const float*)d_in[1];
    const int*   src     = (const int*)d_in[2];
    const int*   tgt     = (const int*)d_in[3];
    const int*   seg     = (const int*)d_in[4];
    const float* gcn_w   = (const float*)d_in[7];
    const float* e1_w0   = (const float*)d_in[8];
    const float* e1_b0   = (const float*)d_in[9];
    const float* e1_w1   = (const float*)d_in[10];
    const float* e1_b1   = (const float*)d_in[11];
    const float* e1_wk   = (const float*)d_in[12];
    const float* e1_bk   = (const float*)d_in[13];
    const float* e1_root = (const float*)d_in[14];
    const float* e1_bias = (const float*)d_in[15];
    const float* e2_w0   = (const float*)d_in[16];
    const float* e2_b0   = (const float*)d_in[17];
    const float* e2_w1   = (const float*)d_in[18];
    const float* e2_b1   = (const float*)d_in[19];
    const float* e2_wk   = (const float*)d_in[20];
    const float* e2_bk   = (const float*)d_in[21];
    const float* e2_root = (const float*)d_in[22];
    const float* e2_bias = (const float*)d_in[23];
    const float* gcn_W   = (const float*)d_in[24];
    const float* gcn_b   = (const float*)d_in[25];
    float* out = (float*)d_out;

    float*    ws    = (float*)d_ws;
    float*    x1    = ws;                                   // [N,32]
    float*    xw    = x1 + (size_t)N_NODES * 32;            // [N,32]
    unsigned* msg1  = (unsigned*)(xw + (size_t)N_NODES * 32);   // E*16 u32
    unsigned* msg2  = msg1 + (size_t)E_EDGES * 16;          // E*32 u32
    unsigned* h2buf = msg2 + (size_t)E_EDGES * 32;          // E*16 u32 (32 bf16/edge)
    short*    wbt2  = (short*)(h2buf + (size_t)E_EDGES * 16);// 65536 bf16
    short*    wbt1  = wbt2 + 65536;                         // 8192 bf16
    int*      deg   = (int*)(wbt1 + 8192);                  // N
    int*      off   = deg + N_NODES;                        // N+1 (+pad)
    int*      cursor= off + N_NODES + 16;                   // N
    int*      srcp  = cursor + N_NODES;                     // E
    float*    gwp   = (float*)(srcp + E_EDGES);             // E

    hipMemsetAsync(deg, 0, N_NODES * sizeof(int), stream);
    hipMemsetAsync(out, 0, (size_t)out_size * sizeof(float), stream);

    prep<<<E_EDGES / 256, 256, 0, stream>>>(e2_wk, e2_bk, e1_wk, e1_bk, tgt,
        wbt2, wbt1, deg);
    csr_scan<<<1, 1024, 0, stream>>>(deg, off, cursor);

    ecc1_mfma<<<E_EDGES / 256, 256, 0, stream>>>(x, e, src, tgt, gcn_w,
        e1_w0, e1_b0, e1_w1, e1_b1, e2_w0, e2_b0, e2_w1, e2_b1,
        wbt1, cursor, srcp, gwp, msg1, h2buf);
    gather1<<<N_NODES / 16, 256, 0, stream>>>(msg1, off, x, e1_root, e1_bias, x1);
    ecc2_mfma<<<E_EDGES / 128, 256, 0, stream>>>(x1, srcp, h2buf, wbt2, msg2);
    gather2<<<N_NODES / 32, 256, 0, stream>>>(msg2, off, x1,
        e2_root, e2_bias, gcn_W, xw);
    gcn_pool<<<N_NODES / 8, 256, 0, stream>>>(xw, off, srcp, gwp,
        gcn_w, gcn_b, seg, out);
}

// Round 11
// 230.002 us; speedup vs baseline: 1.1763x; 1.1763x over previous
//
#include <hip/hip_runtime.h>
#include <hip/hip_bf16.h>

#define N_NODES 16384
#define E_EDGES 131072
#define F_IN 6
#define S_DIM 4
#define G_GRAPHS 256
#define H_DIM 30
#define C1 32
#define C2 64
#define C3 32

typedef __attribute__((ext_vector_type(8))) short bf16x8;
typedef __attribute__((ext_vector_type(4))) float f32x4;

__device__ __forceinline__ short f2bf(float f) {
    union { float f; unsigned u; } a; a.f = f;
    unsigned r = a.u + 0x7FFFu + ((a.u >> 16) & 1u);
    return (short)(r >> 16);
}

// pack two f32 -> (bf16(a) low16, bf16(b) high16)
__device__ __forceinline__ unsigned pack2(float a, float b) {
    unsigned ua = __float_as_uint(a) + 0x8000u;
    unsigned ub = __float_as_uint(b) + 0x8000u;
    return __builtin_amdgcn_perm(ub, ua, 0x07060302u);
}

// ---------------------------------------------------------------------------
// prep: wbt1/wbt2 (main-GEMM B), wt (4x 32x32 MLP A-fragments: W^T layouts),
// degree histogram. wt order: [w0a^T][w1a^T][w0b^T][w1b^T], each [m32][k32].
// Stage1: k<4 = W0 rows, k==4 = b0, m==30 row outputs 1.0 (bias channel).
// Stage2: k<30 = W1 rows, k==30 = b1, m==30 row outputs 1.0.
// ---------------------------------------------------------------------------
__global__ __launch_bounds__(256) void prep(
    const float* __restrict__ wk2, const float* __restrict__ bk2,
    const float* __restrict__ wk1, const float* __restrict__ bk1,
    const float* __restrict__ w0a, const float* __restrict__ b0a,
    const float* __restrict__ w1a, const float* __restrict__ b1a,
    const float* __restrict__ w0b, const float* __restrict__ b0b,
    const float* __restrict__ w1b, const float* __restrict__ b1b,
    const int* __restrict__ tgt,
    short* __restrict__ wbt2, short* __restrict__ wbt1,
    short* __restrict__ wt, int* __restrict__ deg)
{
    const int gtid = blockIdx.x * 256 + threadIdx.x;
    if (gtid < 65536) {
        const int idx = gtid;
        const int j = idx & 7, kq = (idx >> 3) & 3, n = (idx >> 5) & 15;
        const int nt = (idx >> 9) & 3, kc = idx >> 11;
        const int c1 = kq * 8 + j, c2 = nt * 16 + n;
        float v = (kc < 30) ? wk2[kc * 2048 + c1 * 64 + c2]
                            : ((kc == 30) ? bk2[c1 * 64 + c2] : 0.f);
        wbt2[idx] = f2bf(v);
    } else if (gtid < 73728) {
        const int i2 = gtid - 65536;
        const int j = i2 & 7, kq = (i2 >> 3) & 3, n = (i2 >> 5) & 15;
        const int nt = (i2 >> 9) & 1, kc = i2 >> 10;
        const int h = kc * 4 + kq, c1 = nt * 16 + n;
        float v = 0.f;
        if (j < 6) {
            if (h < 30) v = wk1[h * 192 + j * 32 + c1];
            else if (h == 30) v = bk1[j * 32 + c1];
        }
        wbt1[i2] = f2bf(v);
    } else if (gtid < 77824) {
        const int i3 = gtid - 73728;
        const int arr = i3 >> 10, idx = i3 & 1023;
        const int m = idx >> 5, k = idx & 31;
        float v = 0.f;
        if (arr == 0 || arr == 2) {           // stage-1 W0^T
            const float* w0 = (arr == 0) ? w0a : w0b;
            const float* b0 = (arr == 0) ? b0a : b0b;
            if (m < 30) v = (k < 4) ? w0[k * 30 + m] : ((k == 4) ? b0[m] : 0.f);
            else if (m == 30) v = (k == 4) ? 1.f : 0.f;
        } else {                              // stage-2 W1^T
            const float* w1 = (arr == 1) ? w1a : w1b;
            const float* b1 = (arr == 1) ? b1a : b1b;
            if (m < 30) v = (k < 30) ? w1[k * 30 + m] : ((k == 30) ? b1[m] : 0.f);
            else if (m == 30) v = (k == 30) ? 1.f : 0.f;
        }
        wt[i3] = f2bf(v);
    }
    atomicAdd(&deg[tgt[gtid]], 1);
}

// single block, 1024 threads, 16 elems/thread exclusive scan over N=16384
__global__ __launch_bounds__(1024) void csr_scan(
    const int* __restrict__ deg, int* __restrict__ off, int* __restrict__ cursor)
{
    __shared__ int s[1024];
    const int t = threadIdx.x;
    const int base = t * 16;
    int loc[16]; int sum = 0;
    #pragma unroll
    for (int i = 0; i < 16; ++i) { loc[i] = sum; sum += deg[base + i]; }
    s[t] = sum;
    __syncthreads();
    int v = sum;
    for (int d = 1; d < 1024; d <<= 1) {
        const int add = (t >= d) ? s[t - d] : 0;
        __syncthreads();
        v += add; s[t] = v;
        __syncthreads();
    }
    const int pre = v - sum;
    #pragma unroll
    for (int i = 0; i < 16; ++i) {
        const int o = pre + loc[i];
        off[base + i] = o; cursor[base + i] = o;
    }
    if (t == 1023) off[N_NODES] = E_EDGES;
}

// ---------------------------------------------------------------------------
// MLP kernel: both edge-MLPs via MFMA (transposed: A=W^T prebuilt, B=edges).
// 256 edges/block, wave-local LDS round-trips. Fused CSR permute.
// Outputs h1buf/h2buf (32 bf16/edge, A-layout, at permuted slot), srcp, gwp.
// ---------------------------------------------------------------------------
__global__ __launch_bounds__(256, 4) void mlp_mfma(
    const float* __restrict__ e, const int* __restrict__ src,
    const int* __restrict__ tgt, const float* __restrict__ gcn_w,
    const short* __restrict__ wt,
    int* __restrict__ cursor, int* __restrict__ srcp, float* __restrict__ gwp,
    unsigned* __restrict__ h1buf, unsigned* __restrict__ h2buf)
{
    __shared__ uint2 s_eb[256];
    __shared__ unsigned short s_h[256 * 40];
    __shared__ int s_perm[256];

    const int t = threadIdx.x;
    const int tile = blockIdx.x * 256;
    {
        const int eid = tile + t;
        const int sv = src[eid];
        const int p = atomicAdd(&cursor[tgt[eid]], 1);
        s_perm[t] = p;
        srcp[p] = sv;
        gwp[p] = gcn_w[eid];
        const float4 ev = *(const float4*)(e + eid * 4);
        s_eb[t] = make_uint2(pack2(ev.x, ev.y), pack2(ev.z, ev.w));
    }
    __syncthreads();

    const int wv = t >> 6, lane = t & 63;
    const int n = lane & 15, quad = lane >> 4;
    const int e0 = wv * 64;
    const int p_out = s_perm[t];

    // stage-1 B-frags (B[k][n=edge]: k0-3 = e feats, k4 = 1, rest 0)
    bf16x8 b1f[4];
    #pragma unroll
    for (int g = 0; g < 4; ++g) {
        union { unsigned u[4]; bf16x8 v; } bf;
        const uint2 eb = s_eb[e0 + g * 16 + n];
        bf.u[0] = (quad == 0) ? eb.x : 0u;
        bf.u[1] = (quad == 0) ? eb.y : 0u;
        bf.u[2] = (quad == 0) ? 0x00003F80u : 0u;   // (1.0, 0) bf16 pair
        bf.u[3] = 0u;
        b1f[g] = bf.v;
    }

    #pragma unroll 1
    for (int ml = 0; ml < 2; ++ml) {
        const short* w0t = wt + ml * 2048;
        const short* w1t = wt + ml * 2048 + 1024;

        // ---- stage 1: h0 ----
        #pragma unroll
        for (int m = 0; m < 2; ++m) {
            const bf16x8 af = *(const bf16x8*)(w0t + (m * 16 + n) * 32 + quad * 8);
            #pragma unroll
            for (int g = 0; g < 4; ++g) {
                f32x4 c = __builtin_amdgcn_mfma_f32_16x16x32_bf16(
                    af, b1f[g], (f32x4){0.f, 0.f, 0.f, 0.f}, 0, 0, 0);
                ushort4 w4;
                w4.x = (unsigned short)f2bf(fmaxf(c[0], 0.f));
                w4.y = (unsigned short)f2bf(fmaxf(c[1], 0.f));
                w4.z = (unsigned short)f2bf(fmaxf(c[2], 0.f));
                w4.w = (unsigned short)f2bf(fmaxf(c[3], 0.f));
                *(ushort4*)&s_h[(e0 + g * 16 + n) * 40 + m * 16 + quad * 4] = w4;
            }
        }
        __syncthreads();
        // ---- stage 2 B-frags from h0 ----
        bf16x8 b2f[4];
        #pragma unroll
        for (int g = 0; g < 4; ++g)
            b2f[g] = *(const bf16x8*)&s_h[(e0 + g * 16 + n) * 40 + quad * 8];
        __syncthreads();
        // ---- stage 2: h1 (overwrites s_h) ----
        #pragma unroll
        for (int m = 0; m < 2; ++m) {
            const bf16x8 af = *(const bf16x8*)(w1t + (m * 16 + n) * 32 + quad * 8);
            #pragma unroll
            for (int g = 0; g < 4; ++g) {
                f32x4 c = __builtin_amdgcn_mfma_f32_16x16x32_bf16(
                    af, b2f[g], (f32x4){0.f, 0.f, 0.f, 0.f}, 0, 0, 0);
                ushort4 w4;
                w4.x = (unsigned short)f2bf(fmaxf(c[0], 0.f));
                w4.y = (unsigned short)f2bf(fmaxf(c[1], 0.f));
                w4.z = (unsigned short)f2bf(fmaxf(c[2], 0.f));
                w4.w = (unsigned short)f2bf(fmaxf(c[3], 0.f));
                *(ushort4*)&s_h[(e0 + g * 16 + n) * 40 + m * 16 + quad * 4] = w4;
            }
        }
        __syncthreads();
        // ---- per-thread coalesced store of this edge's 32 bf16 ----
        unsigned* dst = (ml == 0 ? h1buf : h2buf) + (size_t)p_out * 16;
        #pragma unroll
        for (int q = 0; q < 4; ++q)
            *(uint4*)(dst + q * 4) = *(const uint4*)&s_h[t * 40 + q * 8];
        __syncthreads();
    }
}

// ---------------------------------------------------------------------------
// ECC1: pure MFMA GEMM over CSR-permuted edges (h1 precomputed).
// ---------------------------------------------------------------------------
__global__ __launch_bounds__(256, 6) void ecc1_gemm(
    const float* __restrict__ x, const int* __restrict__ srcp,
    const unsigned* __restrict__ h1buf,
    const short* __restrict__ wbt1, unsigned* __restrict__ msg1)
{
    __shared__ unsigned short s_h1b[128 * 40];
    __shared__ unsigned short s_xb[128 * 8];

    const int t = threadIdx.x;
    const int tile = blockIdx.x * 128;
    const int el = t & 127, hf = t >> 7;
    {
        const int p = tile + el;
        const uint4* hp = (const uint4*)h1buf + (size_t)p * 4 + hf * 2;
        const uint4 a0 = hp[0], a1 = hp[1];
        *(uint4*)&s_h1b[el * 40 + hf * 16] = a0;
        *(uint4*)&s_h1b[el * 40 + hf * 16 + 8] = a1;
        if (hf == 0) {
            const float2* xp = (const float2*)(x + (size_t)srcp[p] * F_IN);
            const float2 a = xp[0], b = xp[1], c = xp[2];
            *(uint4*)&s_xb[el * 8] =
                make_uint4(pack2(a.x, a.y), pack2(b.x, b.y), pack2(c.x, c.y), 0u);
        }
    }
    __syncthreads();

    const int wv = t >> 6, lane = t & 63;
    const int n = lane & 15, quad = lane >> 4;
    const int e0 = wv * 32;

    float xf[2][8];
    #pragma unroll
    for (int m = 0; m < 2; ++m) {
        const uint4 xv = *(const uint4*)&s_xb[(e0 + m * 16 + n) * 8];
        xf[m][0] = __uint_as_float(xv.x << 16);
        xf[m][1] = __uint_as_float(xv.x & 0xFFFF0000u);
        xf[m][2] = __uint_as_float(xv.y << 16);
        xf[m][3] = __uint_as_float(xv.y & 0xFFFF0000u);
        xf[m][4] = __uint_as_float(xv.z << 16);
        xf[m][5] = __uint_as_float(xv.z & 0xFFFF0000u);
        xf[m][6] = 0.f; xf[m][7] = 0.f;
    }

    f32x4 acc[2][2];
    #pragma unroll
    for (int m = 0; m < 2; ++m) {
        acc[m][0] = (f32x4){0.f, 0.f, 0.f, 0.f};
        acc[m][1] = (f32x4){0.f, 0.f, 0.f, 0.f};
    }

    #pragma unroll
    for (int kc = 0; kc < 8; ++kc) {
        bf16x8 bfr[2];
        #pragma unroll
        for (int nt = 0; nt < 2; ++nt)
            bfr[nt] = *(const bf16x8*)(wbt1 + (((kc * 2 + nt) * 16 + n) << 5) + quad * 8);
        #pragma unroll
        for (int m = 0; m < 2; ++m) {
            const unsigned hv = s_h1b[(e0 + m * 16 + n) * 40 + kc * 4 + quad];
            const float hfv = __uint_as_float(hv << 16);
            union { unsigned u[4]; bf16x8 v; } af;
            #pragma unroll
            for (int i = 0; i < 4; ++i)
                af.u[i] = pack2(hfv * xf[m][2 * i], hfv * xf[m][2 * i + 1]);
            acc[m][0] = __builtin_amdgcn_mfma_f32_16x16x32_bf16(af.v, bfr[0], acc[m][0], 0, 0, 0);
            acc[m][1] = __builtin_amdgcn_mfma_f32_16x16x32_bf16(af.v, bfr[1], acc[m][1], 0, 0, 0);
        }
    }

    #pragma unroll
    for (int m = 0; m < 2; ++m)
        #pragma unroll
        for (int r = 0; r < 4; ++r) {
            const int p = tile + e0 + m * 16 + quad * 4 + r;
            msg1[p * 16 + n] = pack2(acc[m][0][r], acc[m][1][r]);
        }
}

// gather msg1 (sequential, permuted layout) + node update 1 -> x1
__global__ __launch_bounds__(256) void gather1(
    const unsigned* __restrict__ msg1, const int* __restrict__ off,
    const float* __restrict__ x,
    const float* __restrict__ root, const float* __restrict__ bias,
    float* __restrict__ x1)
{
    __shared__ float s_root[192];
    __shared__ float s_b[32];
    const int t = threadIdx.x;
    if (t < 192) s_root[t] = root[t];
    if (t < 32) s_b[t] = bias[t];
    __syncthreads();
    const int v = blockIdx.x * 16 + (t >> 4);
    const int n = t & 15;
    const int o0 = off[v], o1 = off[v + 1];
    float sa = 0.f, sb = 0.f;
    for (int j = o0; j < o1; ++j) {
        const unsigned u = msg1[j * 16 + n];
        sa += __uint_as_float(u << 16);
        sb += __uint_as_float(u & 0xFFFF0000u);
    }
    const float* xr = x + (size_t)v * F_IN;
    float ra = s_b[n], rb = s_b[16 + n];
    #pragma unroll
    for (int f = 0; f < 6; ++f) {
        const float xv = xr[f];
        ra += xv * s_root[f * 32 + n];
        rb += xv * s_root[f * 32 + 16 + n];
    }
    x1[v * 32 + n] = fmaxf(sa + ra, 0.f);
    x1[v * 32 + 16 + n] = fmaxf(sb + rb, 0.f);
}

// ---------------------------------------------------------------------------
// ECC2: pure MFMA GEMM over CSR-permuted edges (unchanged from R9/R10).
// ---------------------------------------------------------------------------
__global__ __launch_bounds__(256, 6) void ecc2_mfma(
    const float* __restrict__ x1, const int* __restrict__ srcp,
    const unsigned* __restrict__ h2buf,
    const short* __restrict__ wbt2, unsigned* __restrict__ msg2)
{
    __shared__ unsigned short s_h1b[128 * 40];
    __shared__ unsigned short s_x1b[128 * 40];

    const int t = threadIdx.x;
    const int tile = blockIdx.x * 128;
    const int el = t & 127, hf = t >> 7;
    {
        const int p = tile + el;
        const uint4* h2p = (const uint4*)h2buf + (size_t)p * 4 + hf * 2;
        const uint4 a0 = h2p[0], a1 = h2p[1];
        *(uint4*)&s_h1b[el * 40 + hf * 16] = a0;
        *(uint4*)&s_h1b[el * 40 + hf * 16 + 8] = a1;

        const float* xp = x1 + (size_t)srcp[p] * C1 + hf * 16;
        uint4* xb = (uint4*)&s_x1b[el * 40];
        #pragma unroll
        for (int q = 0; q < 2; ++q) {
            const float4 v0 = *(const float4*)(xp + q * 8);
            const float4 v1 = *(const float4*)(xp + q * 8 + 4);
            xb[hf * 2 + q] = make_uint4(pack2(v0.x, v0.y), pack2(v0.z, v0.w),
                                        pack2(v1.x, v1.y), pack2(v1.z, v1.w));
        }
    }
    __syncthreads();

    const int wv = t >> 6, lane = t & 63;
    const int n = lane & 15, quad = lane >> 4;
    const int e0 = wv * 32;

    float xf[2][8];
    #pragma unroll
    for (int m = 0; m < 2; ++m) {
        const uint4 xv = *(const uint4*)&s_x1b[(e0 + m * 16 + n) * 40 + quad * 8];
        xf[m][0] = __uint_as_float(xv.x << 16);
        xf[m][1] = __uint_as_float(xv.x & 0xFFFF0000u);
        xf[m][2] = __uint_as_float(xv.y << 16);
        xf[m][3] = __uint_as_float(xv.y & 0xFFFF0000u);
        xf[m][4] = __uint_as_float(xv.z << 16);
        xf[m][5] = __uint_as_float(xv.z & 0xFFFF0000u);
        xf[m][6] = __uint_as_float(xv.w << 16);
        xf[m][7] = __uint_as_float(xv.w & 0xFFFF0000u);
    }

    f32x4 acc[2][4];
    #pragma unroll
    for (int m = 0; m < 2; ++m)
        #pragma unroll
        for (int nt = 0; nt < 4; ++nt) acc[m][nt] = (f32x4){0.f, 0.f, 0.f, 0.f};

    #pragma unroll 4
    for (int kc = 0; kc < 32; ++kc) {
        bf16x8 bfr[4];
        #pragma unroll
        for (int nt = 0; nt < 4; ++nt)
            bfr[nt] = *(const bf16x8*)(wbt2 + (((kc * 4 + nt) * 16 + n) << 5) + quad * 8);
        #pragma unroll
        for (int m = 0; m < 2; ++m) {
            const unsigned hv = s_h1b[(e0 + m * 16 + n) * 40 + kc];
            const float hfv = __uint_as_float(hv << 16);
            union { unsigned u[4]; bf16x8 v; } af;
            #pragma unroll
            for (int i = 0; i < 4; ++i)
                af.u[i] = pack2(hfv * xf[m][2 * i], hfv * xf[m][2 * i + 1]);
            #pragma unroll
            for (int nt = 0; nt < 4; ++nt)
                acc[m][nt] = __builtin_amdgcn_mfma_f32_16x16x32_bf16(af.v, bfr[nt], acc[m][nt], 0, 0, 0);
        }
    }

    #pragma unroll
    for (int m = 0; m < 2; ++m)
        #pragma unroll
        for (int r = 0; r < 4; ++r) {
            const int p = tile + e0 + m * 16 + quad * 4 + r;
            uint2 val;
            val.x = pack2(acc[m][0][r], acc[m][1][r]);
            val.y = pack2(acc[m][2][r], acc[m][3][r]);
            *(uint2*)&msg2[p * 32 + n * 2] = val;
        }
}

// gather msg2 (sequential) + node update 2 + xw = x2 @ gcn_W -> xw.
// 32 nodes/block: weights staged once, reused 4x.
__global__ __launch_bounds__(256) void gather2(
    const unsigned* __restrict__ msg2, const int* __restrict__ off,
    const float* __restrict__ x1,
    const float* __restrict__ root, const float* __restrict__ bias,
    const float* __restrict__ W, float* __restrict__ xw)
{
    __shared__ float s_root[2048], s_W[2048], s_b[64];
    __shared__ float s_x2[8][68];
    __shared__ float s_x1v[256];
    const int t = threadIdx.x;
    const int nb = blockIdx.x * 32;
    for (int i = t; i < 2048; i += 256) { s_root[i] = root[i]; s_W[i] = W[i]; }
    if (t < 64) s_b[t] = bias[t];

    const int lv = t >> 5;
    const int j5 = t & 31;
    const int n = j5 >> 1, p = j5 & 1;
    const int ca = p * 32 + n, cb = p * 32 + 16 + n;

    #pragma unroll 1
    for (int rd = 0; rd < 4; ++rd) {
        s_x1v[t] = x1[(nb + rd * 8) * 32 + t];
        __syncthreads();
        const int v = nb + rd * 8 + lv;
        const int o0 = off[v], o1 = off[v + 1];
        float sa = 0.f, sb = 0.f;
        for (int j = o0; j < o1; ++j) {
            const unsigned u = msg2[j * 32 + j5];
            sa += __uint_as_float(u << 16);
            sb += __uint_as_float(u & 0xFFFF0000u);
        }
        float ra = s_b[ca], rb = s_b[cb];
        #pragma unroll 8
        for (int k = 0; k < 32; ++k) {
            const float xv = s_x1v[lv * 32 + k];
            ra += xv * s_root[k * 64 + ca];
            rb += xv * s_root[k * 64 + cb];
        }
        s_x2[lv][ca] = fmaxf(sa + ra, 0.f);
        s_x2[lv][cb] = fmaxf(sb + rb, 0.f);
        __syncthreads();
        float av = 0.f;
        #pragma unroll 8
        for (int k = 0; k < 64; ++k) av += s_x2[lv][k] * s_W[k * 32 + j5];
        xw[v * 32 + j5] = av;
    }
}

// GCN gather (CSR-ordered srcp/gwp, sequential) + relu + global pool
__global__ __launch_bounds__(256) void gcn_pool(
    const float* __restrict__ xw, const int* __restrict__ off,
    const int* __restrict__ srcp, const float* __restrict__ gwp,
    const float* __restrict__ gw, const float* __restrict__ gb,
    const int* __restrict__ seg, float* __restrict__ out)
{
    __shared__ float s_gb[32];
    const int t = threadIdx.x;
    if (t < 32) s_gb[t] = gb[t];
    __syncthreads();
    const int v = blockIdx.x * 8 + (t >> 5);
    const int c = t & 31;
    const int o0 = off[v], o1 = off[v + 1];
    float s = gw[E_EDGES + v] * xw[v * 32 + c];   // self loop
    for (int j = o0; j < o1; ++j)
        s += gwp[j] * xw[srcp[j] * 32 + c];
    const float val = fmaxf(s + s_gb[c], 0.f);
    atomicAdd(&out[seg[v] * 32 + c], val);
}

extern "C" void kernel_launch(void* const* d_in, const int* in_sizes, int n_in,
                              void* d_out, int out_size, void* d_ws, size_t ws_size,
                              hipStream_t stream)
{
    const float* x       = (const float*)d_in[0];
    const float* e       = (const float*)d_in[1];
    const int*   src     = (const int*)d_in[2];
    const int*   tgt     = (const int*)d_in[3];
    const int*   seg     = (const int*)d_in[4];
    const float* gcn_w   = (const float*)d_in[7];
    const float* e1_w0   = (const float*)d_in[8];
    const float* e1_b0   = (const float*)d_in[9];
    const float* e1_w1   = (const float*)d_in[10];
    const float* e1_b1   = (const float*)d_in[11];
    const float* e1_wk   = (const float*)d_in[12];
    const float* e1_bk   = (const float*)d_in[13];
    const float* e1_root = (const float*)d_in[14];
    const float* e1_bias = (const float*)d_in[15];
    const float* e2_w0   = (const float*)d_in[16];
    const float* e2_b0   = (const float*)d_in[17];
    const float* e2_w1   = (const float*)d_in[18];
    const float* e2_b1   = (const float*)d_in[19];
    const float* e2_wk   = (const float*)d_in[20];
    const float* e2_bk   = (const float*)d_in[21];
    const float* e2_root = (const float*)d_in[22];
    const float* e2_bias = (const float*)d_in[23];
    const float* gcn_W   = (const float*)d_in[24];
    const float* gcn_b   = (const float*)d_in[25];
    float* out = (float*)d_out;

    float*    ws    = (float*)d_ws;
    float*    x1    = ws;                                   // [N,32]
    float*    xw    = x1 + (size_t)N_NODES * 32;            // [N,32]
    unsigned* msg1  = (unsigned*)(xw + (size_t)N_NODES * 32);   // E*16 u32
    unsigned* msg2  = msg1 + (size_t)E_EDGES * 16;          // E*32 u32
    unsigned* h1buf = msg2 + (size_t)E_EDGES * 32;          // E*16 u32
    unsigned* h2buf = h1buf + (size_t)E_EDGES * 16;         // E*16 u32
    short*    wbt2  = (short*)(h2buf + (size_t)E_EDGES * 16);// 65536 bf16
    short*    wbt1  = wbt2 + 65536;                         // 8192 bf16
    short*    wt    = wbt1 + 8192;                          // 4096 bf16
    int*      deg   = (int*)(wt + 4096);                    // N
    int*      off   = deg + N_NODES;                        // N+1 (+pad)
    int*      cursor= off + N_NODES + 16;                   // N
    int*      srcp  = cursor + N_NODES;                     // E
    float*    gwp   = (float*)(srcp + E_EDGES);             // E

    hipMemsetAsync(deg, 0, N_NODES * sizeof(int), stream);
    hipMemsetAsync(out, 0, (size_t)out_size * sizeof(float), stream);

    prep<<<E_EDGES / 256, 256, 0, stream>>>(
        e2_wk, e2_bk, e1_wk, e1_bk,
        e1_w0, e1_b0, e1_w1, e1_b1, e2_w0, e2_b0, e2_w1, e2_b1,
        tgt, wbt2, wbt1, wt, deg);
    csr_scan<<<1, 1024, 0, stream>>>(deg, off, cursor);

    mlp_mfma<<<E_EDGES / 256, 256, 0, stream>>>(e, src, tgt, gcn_w, wt,
        cursor, srcp, gwp, h1buf, h2buf);
    ecc1_gemm<<<E_EDGES / 128, 256, 0, stream>>>(x, srcp, h1buf, wbt1, msg1);
    gather1<<<N_NODES / 16, 256, 0, stream>>>(msg1, off, x, e1_root, e1_bias, x1);
    ecc2_mfma<<<E_EDGES / 128, 256, 0, stream>>>(x1, srcp, h2buf, wbt2, msg2);
    gather2<<<N_NODES / 32, 256, 0, stream>>>(msg2, off, x1,
        e2_root, e2_bias, gcn_W, xw);
    gcn_pool<<<N_NODES / 8, 256, 0, stream>>>(xw, off, srcp, gwp,
        gcn_w, gcn_b, seg, out);
}

// Round 12
// 214.219 us; speedup vs baseline: 1.2630x; 1.0737x over previous
//
#include <hip/hip_runtime.h>
#include <hip/hip_bf16.h>

#define N_NODES 16384
#define E_EDGES 131072
#define F_IN 6
#define S_DIM 4
#define G_GRAPHS 256
#define H_DIM 30
#define C1 32
#define C2 64
#define C3 32

typedef __attribute__((ext_vector_type(8))) short bf16x8;
typedef __attribute__((ext_vector_type(4))) float f32x4;

__device__ __forceinline__ short f2bf(float f) {
    union { float f; unsigned u; } a; a.f = f;
    unsigned r = a.u + 0x7FFFu + ((a.u >> 16) & 1u);
    return (short)(r >> 16);
}

// pack two f32 -> (bf16(a) low16, bf16(b) high16)
__device__ __forceinline__ unsigned pack2(float a, float b) {
    unsigned ua = __float_as_uint(a) + 0x8000u;
    unsigned ub = __float_as_uint(b) + 0x8000u;
    return __builtin_amdgcn_perm(ub, ua, 0x07060302u);
}

// async global->LDS 16B per lane; lds base wave-uniform, lane offset = lane*16B.
__device__ __forceinline__ void async_copy16(const void* g, void* l) {
    __builtin_amdgcn_global_load_lds(
        (const __attribute__((address_space(1))) unsigned int*)g,
        (__attribute__((address_space(3))) unsigned int*)l, 16, 0, 0);
}

// ---------------------------------------------------------------------------
// prep: wbt1/wbt2 (main-GEMM B), wt (4x 32x32 MLP A-fragments), deg histogram.
// ---------------------------------------------------------------------------
__global__ __launch_bounds__(256) void prep(
    const float* __restrict__ wk2, const float* __restrict__ bk2,
    const float* __restrict__ wk1, const float* __restrict__ bk1,
    const float* __restrict__ w0a, const float* __restrict__ b0a,
    const float* __restrict__ w1a, const float* __restrict__ b1a,
    const float* __restrict__ w0b, const float* __restrict__ b0b,
    const float* __restrict__ w1b, const float* __restrict__ b1b,
    const int* __restrict__ tgt,
    short* __restrict__ wbt2, short* __restrict__ wbt1,
    short* __restrict__ wt, int* __restrict__ deg)
{
    const int gtid = blockIdx.x * 256 + threadIdx.x;
    if (gtid < 65536) {
        const int idx = gtid;
        const int j = idx & 7, kq = (idx >> 3) & 3, n = (idx >> 5) & 15;
        const int nt = (idx >> 9) & 3, kc = idx >> 11;
        const int c1 = kq * 8 + j, c2 = nt * 16 + n;
        float v = (kc < 30) ? wk2[kc * 2048 + c1 * 64 + c2]
                            : ((kc == 30) ? bk2[c1 * 64 + c2] : 0.f);
        wbt2[idx] = f2bf(v);
    } else if (gtid < 73728) {
        const int i2 = gtid - 65536;
        const int j = i2 & 7, kq = (i2 >> 3) & 3, n = (i2 >> 5) & 15;
        const int nt = (i2 >> 9) & 1, kc = i2 >> 10;
        const int h = kc * 4 + kq, c1 = nt * 16 + n;
        float v = 0.f;
        if (j < 6) {
            if (h < 30) v = wk1[h * 192 + j * 32 + c1];
            else if (h == 30) v = bk1[j * 32 + c1];
        }
        wbt1[i2] = f2bf(v);
    } else if (gtid < 77824) {
        const int i3 = gtid - 73728;
        const int arr = i3 >> 10, idx = i3 & 1023;
        const int m = idx >> 5, k = idx & 31;
        float v = 0.f;
        if (arr == 0 || arr == 2) {           // stage-1 W0^T
            const float* w0 = (arr == 0) ? w0a : w0b;
            const float* b0 = (arr == 0) ? b0a : b0b;
            if (m < 30) v = (k < 4) ? w0[k * 30 + m] : ((k == 4) ? b0[m] : 0.f);
            else if (m == 30) v = (k == 4) ? 1.f : 0.f;
        } else {                              // stage-2 W1^T
            const float* w1 = (arr == 1) ? w1a : w1b;
            const float* b1 = (arr == 1) ? b1a : b1b;
            if (m < 30) v = (k < 30) ? w1[k * 30 + m] : ((k == 30) ? b1[m] : 0.f);
            else if (m == 30) v = (k == 30) ? 1.f : 0.f;
        }
        wt[i3] = f2bf(v);
    }
    atomicAdd(&deg[tgt[gtid]], 1);
}

// single block, 1024 threads, 16 elems/thread exclusive scan over N=16384
__global__ __launch_bounds__(1024) void csr_scan(
    const int* __restrict__ deg, int* __restrict__ off, int* __restrict__ cursor)
{
    __shared__ int s[1024];
    const int t = threadIdx.x;
    const int base = t * 16;
    int loc[16]; int sum = 0;
    #pragma unroll
    for (int i = 0; i < 16; ++i) { loc[i] = sum; sum += deg[base + i]; }
    s[t] = sum;
    __syncthreads();
    int v = sum;
    for (int d = 1; d < 1024; d <<= 1) {
        const int add = (t >= d) ? s[t - d] : 0;
        __syncthreads();
        v += add; s[t] = v;
        __syncthreads();
    }
    const int pre = v - sum;
    #pragma unroll
    for (int i = 0; i < 16; ++i) {
        const int o = pre + loc[i];
        off[base + i] = o; cursor[base + i] = o;
    }
    if (t == 1023) off[N_NODES] = E_EDGES;
}

// ---------------------------------------------------------------------------
// ECC1 fused: CSR permute + both MFMA edge-MLPs + ECC1 GEMM.
// MLP2 (pass 0) -> h2buf at permuted slot; MLP1 (pass 1) stays in LDS and
// feeds the GEMM directly. msg1 stored at permuted slot.
// ---------------------------------------------------------------------------
__global__ __launch_bounds__(256, 2) void ecc1_fused(
    const float* __restrict__ x, const float* __restrict__ e,
    const int* __restrict__ src, const int* __restrict__ tgt,
    const float* __restrict__ gcn_w, const short* __restrict__ wt,
    const short* __restrict__ wbt1,
    int* __restrict__ cursor, int* __restrict__ srcp, float* __restrict__ gwp,
    unsigned* __restrict__ msg1, unsigned* __restrict__ h2buf)
{
    __shared__ uint2 s_eb[256];
    __shared__ unsigned short s_h[256 * 40];
    __shared__ unsigned short s_xb[256 * 8];
    __shared__ int s_perm[256];

    const int t = threadIdx.x;
    const int tile = blockIdx.x * 256;

    // ---- phase A: permute + stage e and x[src] ----
    {
        const int eid = tile + t;
        const int sv = src[eid];
        const int p = atomicAdd(&cursor[tgt[eid]], 1);
        s_perm[t] = p;
        srcp[p] = sv;
        gwp[p] = gcn_w[eid];
        const float4 ev = *(const float4*)(e + eid * 4);
        s_eb[t] = make_uint2(pack2(ev.x, ev.y), pack2(ev.z, ev.w));
        const float2* xp = (const float2*)(x + (size_t)sv * F_IN);
        const float2 a = xp[0], b = xp[1], c = xp[2];
        *(uint4*)&s_xb[t * 8] =
            make_uint4(pack2(a.x, a.y), pack2(b.x, b.y), pack2(c.x, c.y), 0u);
    }
    __syncthreads();

    const int wv = t >> 6, lane = t & 63;
    const int n = lane & 15, quad = lane >> 4;
    const int e0 = wv * 64;
    const int p_out = s_perm[t];

    // stage-1 MLP B-frags (edge features), built once, reused by both passes
    bf16x8 b1f[4];
    #pragma unroll
    for (int g = 0; g < 4; ++g) {
        union { unsigned u[4]; bf16x8 v; } bf;
        const uint2 eb = s_eb[e0 + g * 16 + n];
        bf.u[0] = (quad == 0) ? eb.x : 0u;
        bf.u[1] = (quad == 0) ? eb.y : 0u;
        bf.u[2] = (quad == 0) ? 0x00003F80u : 0u;
        bf.u[3] = 0u;
        b1f[g] = bf.v;
    }

    // ---- passes: pass0 = MLP2 (store h2buf), pass1 = MLP1 (keep in s_h) ----
    #pragma unroll 1
    for (int pass = 0; pass < 2; ++pass) {
        const int ml = 1 - pass;
        const short* w0t = wt + ml * 2048;
        const short* w1t = wt + ml * 2048 + 1024;

        #pragma unroll
        for (int m = 0; m < 2; ++m) {
            const bf16x8 af = *(const bf16x8*)(w0t + (m * 16 + n) * 32 + quad * 8);
            #pragma unroll
            for (int g = 0; g < 4; ++g) {
                f32x4 c = __builtin_amdgcn_mfma_f32_16x16x32_bf16(
                    af, b1f[g], (f32x4){0.f, 0.f, 0.f, 0.f}, 0, 0, 0);
                ushort4 w4;
                w4.x = (unsigned short)f2bf(fmaxf(c[0], 0.f));
                w4.y = (unsigned short)f2bf(fmaxf(c[1], 0.f));
                w4.z = (unsigned short)f2bf(fmaxf(c[2], 0.f));
                w4.w = (unsigned short)f2bf(fmaxf(c[3], 0.f));
                *(ushort4*)&s_h[(e0 + g * 16 + n) * 40 + m * 16 + quad * 4] = w4;
            }
        }
        __syncthreads();
        bf16x8 b2f[4];
        #pragma unroll
        for (int g = 0; g < 4; ++g)
            b2f[g] = *(const bf16x8*)&s_h[(e0 + g * 16 + n) * 40 + quad * 8];
        __syncthreads();
        #pragma unroll
        for (int m = 0; m < 2; ++m) {
            const bf16x8 af = *(const bf16x8*)(w1t + (m * 16 + n) * 32 + quad * 8);
            #pragma unroll
            for (int g = 0; g < 4; ++g) {
                f32x4 c = __builtin_amdgcn_mfma_f32_16x16x32_bf16(
                    af, b2f[g], (f32x4){0.f, 0.f, 0.f, 0.f}, 0, 0, 0);
                ushort4 w4;
                w4.x = (unsigned short)f2bf(fmaxf(c[0], 0.f));
                w4.y = (unsigned short)f2bf(fmaxf(c[1], 0.f));
                w4.z = (unsigned short)f2bf(fmaxf(c[2], 0.f));
                w4.w = (unsigned short)f2bf(fmaxf(c[3], 0.f));
                *(ushort4*)&s_h[(e0 + g * 16 + n) * 40 + m * 16 + quad * 4] = w4;
            }
        }
        __syncthreads();
        if (pass == 0) {
            unsigned* dst = h2buf + (size_t)p_out * 16;
            #pragma unroll
            for (int q = 0; q < 4; ++q)
                *(uint4*)(dst + q * 4) = *(const uint4*)&s_h[t * 40 + q * 8];
            __syncthreads();
        }
    }

    // ---- ECC1 GEMM: msg1 = (h1 x xpad8) @ W1', m=4, nt=2, kc=8 ----
    float xf[4][8];
    #pragma unroll
    for (int m = 0; m < 4; ++m) {
        const uint4 xv = *(const uint4*)&s_xb[(e0 + m * 16 + n) * 8];
        xf[m][0] = __uint_as_float(xv.x << 16);
        xf[m][1] = __uint_as_float(xv.x & 0xFFFF0000u);
        xf[m][2] = __uint_as_float(xv.y << 16);
        xf[m][3] = __uint_as_float(xv.y & 0xFFFF0000u);
        xf[m][4] = __uint_as_float(xv.z << 16);
        xf[m][5] = __uint_as_float(xv.z & 0xFFFF0000u);
        xf[m][6] = 0.f; xf[m][7] = 0.f;
    }

    f32x4 acc[4][2];
    #pragma unroll
    for (int m = 0; m < 4; ++m) {
        acc[m][0] = (f32x4){0.f, 0.f, 0.f, 0.f};
        acc[m][1] = (f32x4){0.f, 0.f, 0.f, 0.f};
    }

    #pragma unroll
    for (int kc = 0; kc < 8; ++kc) {
        bf16x8 bfr[2];
        #pragma unroll
        for (int nt = 0; nt < 2; ++nt)
            bfr[nt] = *(const bf16x8*)(wbt1 + (((kc * 2 + nt) * 16 + n) << 5) + quad * 8);
        #pragma unroll
        for (int m = 0; m < 4; ++m) {
            const unsigned hv = s_h[(e0 + m * 16 + n) * 40 + kc * 4 + quad];
            const float hfv = __uint_as_float(hv << 16);
            union { unsigned u[4]; bf16x8 v; } af;
            #pragma unroll
            for (int i = 0; i < 4; ++i)
                af.u[i] = pack2(hfv * xf[m][2 * i], hfv * xf[m][2 * i + 1]);
            acc[m][0] = __builtin_amdgcn_mfma_f32_16x16x32_bf16(af.v, bfr[0], acc[m][0], 0, 0, 0);
            acc[m][1] = __builtin_amdgcn_mfma_f32_16x16x32_bf16(af.v, bfr[1], acc[m][1], 0, 0, 0);
        }
    }

    #pragma unroll
    for (int m = 0; m < 4; ++m)
        #pragma unroll
        for (int r = 0; r < 4; ++r) {
            const int p = s_perm[e0 + m * 16 + quad * 4 + r];
            msg1[p * 16 + n] = pack2(acc[m][0][r], acc[m][1][r]);
        }
}

// gather msg1 (sequential, permuted layout) + node update 1 -> x1
__global__ __launch_bounds__(256) void gather1(
    const unsigned* __restrict__ msg1, const int* __restrict__ off,
    const float* __restrict__ x,
    const float* __restrict__ root, const float* __restrict__ bias,
    float* __restrict__ x1)
{
    __shared__ float s_root[192];
    __shared__ float s_b[32];
    const int t = threadIdx.x;
    if (t < 192) s_root[t] = root[t];
    if (t < 32) s_b[t] = bias[t];
    __syncthreads();
    const int v = blockIdx.x * 16 + (t >> 4);
    const int n = t & 15;
    const int o0 = off[v], o1 = off[v + 1];
    float sa = 0.f, sb = 0.f;
    for (int j = o0; j < o1; ++j) {
        const unsigned u = msg1[j * 16 + n];
        sa += __uint_as_float(u << 16);
        sb += __uint_as_float(u & 0xFFFF0000u);
    }
    const float* xr = x + (size_t)v * F_IN;
    float ra = s_b[n], rb = s_b[16 + n];
    #pragma unroll
    for (int f = 0; f < 6; ++f) {
        const float xv = xr[f];
        ra += xv * s_root[f * 32 + n];
        rb += xv * s_root[f * 32 + 16 + n];
    }
    x1[v * 32 + n] = fmaxf(sa + ra, 0.f);
    x1[v * 32 + 16 + n] = fmaxf(sb + rb, 0.f);
}

// ---------------------------------------------------------------------------
// ECC2: pure MFMA GEMM over CSR-permuted edges; wbt2 LDS-staged via
// global_load_lds, double-buffered 8 KB chunks (2 kc each) shared by 4 waves.
// ---------------------------------------------------------------------------
__global__ __launch_bounds__(256, 4) void ecc2_mfma(
    const float* __restrict__ x1, const int* __restrict__ srcp,
    const unsigned* __restrict__ h2buf,
    const short* __restrict__ wbt2, unsigned* __restrict__ msg2)
{
    __shared__ unsigned short s_h1b[128 * 40];
    __shared__ unsigned short s_x1b[128 * 40];
    __shared__ short s_wb[2][4096];

    const int t = threadIdx.x;
    const int tile = blockIdx.x * 128;
    const int el = t & 127, hf = t >> 7;
    const int wv = t >> 6, lane = t & 63;

    // prefetch chunk 0 (kc 0,1): 8 KB = 4 waves x 2 insts x 1 KB
    #pragma unroll
    for (int r = 0; r < 2; ++r)
        async_copy16(wbt2 + (wv * 2 + r) * 512 + lane * 8,
                     s_wb[0] + (wv * 2 + r) * 512);

    // ---- phase A: stage h1_2 (coalesced) + x1[srcp] (random) ----
    {
        const int p = tile + el;
        const uint4* h2p = (const uint4*)h2buf + (size_t)p * 4 + hf * 2;
        const uint4 a0 = h2p[0], a1 = h2p[1];
        *(uint4*)&s_h1b[el * 40 + hf * 16] = a0;
        *(uint4*)&s_h1b[el * 40 + hf * 16 + 8] = a1;

        const float* xp = x1 + (size_t)srcp[p] * C1 + hf * 16;
        uint4* xb = (uint4*)&s_x1b[el * 40];
        #pragma unroll
        for (int q = 0; q < 2; ++q) {
            const float4 v0 = *(const float4*)(xp + q * 8);
            const float4 v1 = *(const float4*)(xp + q * 8 + 4);
            xb[hf * 2 + q] = make_uint4(pack2(v0.x, v0.y), pack2(v0.z, v0.w),
                                        pack2(v1.x, v1.y), pack2(v1.z, v1.w));
        }
    }
    __syncthreads();   // drains phase-A stores and chunk-0 async copy

    const int n = lane & 15, quad = lane >> 4;
    const int e0 = wv * 32;

    float xf[2][8];
    #pragma unroll
    for (int m = 0; m < 2; ++m) {
        const uint4 xv = *(const uint4*)&s_x1b[(e0 + m * 16 + n) * 40 + quad * 8];
        xf[m][0] = __uint_as_float(xv.x << 16);
        xf[m][1] = __uint_as_float(xv.x & 0xFFFF0000u);
        xf[m][2] = __uint_as_float(xv.y << 16);
        xf[m][3] = __uint_as_float(xv.y & 0xFFFF0000u);
        xf[m][4] = __uint_as_float(xv.z << 16);
        xf[m][5] = __uint_as_float(xv.z & 0xFFFF0000u);
        xf[m][6] = __uint_as_float(xv.w << 16);
        xf[m][7] = __uint_as_float(xv.w & 0xFFFF0000u);
    }

    f32x4 acc[2][4];
    #pragma unroll
    for (int m = 0; m < 2; ++m)
        #pragma unroll
        for (int nt = 0; nt < 4; ++nt) acc[m][nt] = (f32x4){0.f, 0.f, 0.f, 0.f};

    #pragma unroll 1
    for (int c = 0; c < 16; ++c) {
        if (c < 15) {
            #pragma unroll
            for (int r = 0; r < 2; ++r)
                async_copy16(wbt2 + (c + 1) * 4096 + (wv * 2 + r) * 512 + lane * 8,
                             s_wb[(c + 1) & 1] + (wv * 2 + r) * 512);
        }
        const short* wb = s_wb[c & 1];
        #pragma unroll
        for (int kl = 0; kl < 2; ++kl) {
            const int kc = c * 2 + kl;
            bf16x8 bfr[4];
            #pragma unroll
            for (int nt = 0; nt < 4; ++nt)
                bfr[nt] = *(const bf16x8*)(wb + ((kl * 4 + nt) * 16 + n) * 32 + quad * 8);
            #pragma unroll
            for (int m = 0; m < 2; ++m) {
                const unsigned hv = s_h1b[(e0 + m * 16 + n) * 40 + kc];
                const float hfv = __uint_as_float(hv << 16);
                union { unsigned u[4]; bf16x8 v; } af;
                #pragma unroll
                for (int i = 0; i < 4; ++i)
                    af.u[i] = pack2(hfv * xf[m][2 * i], hfv * xf[m][2 * i + 1]);
                #pragma unroll
                for (int nt = 0; nt < 4; ++nt)
                    acc[m][nt] = __builtin_amdgcn_mfma_f32_16x16x32_bf16(af.v, bfr[nt], acc[m][nt], 0, 0, 0);
            }
        }
        __syncthreads();   // all waves done with buf (c&1); prefetch c+1 drained
    }

    #pragma unroll
    for (int m = 0; m < 2; ++m)
        #pragma unroll
        for (int r = 0; r < 4; ++r) {
            const int p = tile + e0 + m * 16 + quad * 4 + r;
            uint2 val;
            val.x = pack2(acc[m][0][r], acc[m][1][r]);
            val.y = pack2(acc[m][2][r], acc[m][3][r]);
            *(uint2*)&msg2[p * 32 + n * 2] = val;
        }
}

// gather msg2 (sequential) + node update 2 + xw = x2 @ gcn_W -> xw.
__global__ __launch_bounds__(256) void gather2(
    const unsigned* __restrict__ msg2, const int* __restrict__ off,
    const float* __restrict__ x1,
    const float* __restrict__ root, const float* __restrict__ bias,
    const float* __restrict__ W, float* __restrict__ xw)
{
    __shared__ float s_root[2048], s_W[2048], s_b[64];
    __shared__ float s_x2[8][68];
    __shared__ float s_x1v[256];
    const int t = threadIdx.x;
    const int nb = blockIdx.x * 32;
    for (int i = t; i < 2048; i += 256) { s_root[i] = root[i]; s_W[i] = W[i]; }
    if (t < 64) s_b[t] = bias[t];

    const int lv = t >> 5;
    const int j5 = t & 31;
    const int n = j5 >> 1, p = j5 & 1;
    const int ca = p * 32 + n, cb = p * 32 + 16 + n;

    #pragma unroll 1
    for (int rd = 0; rd < 4; ++rd) {
        s_x1v[t] = x1[(nb + rd * 8) * 32 + t];
        __syncthreads();
        const int v = nb + rd * 8 + lv;
        const int o0 = off[v], o1 = off[v + 1];
        float sa = 0.f, sb = 0.f;
        for (int j = o0; j < o1; ++j) {
            const unsigned u = msg2[j * 32 + j5];
            sa += __uint_as_float(u << 16);
            sb += __uint_as_float(u & 0xFFFF0000u);
        }
        float ra = s_b[ca], rb = s_b[cb];
        #pragma unroll 8
        for (int k = 0; k < 32; ++k) {
            const float xv = s_x1v[lv * 32 + k];
            ra += xv * s_root[k * 64 + ca];
            rb += xv * s_root[k * 64 + cb];
        }
        s_x2[lv][ca] = fmaxf(sa + ra, 0.f);
        s_x2[lv][cb] = fmaxf(sb + rb, 0.f);
        __syncthreads();
        float av = 0.f;
        #pragma unroll 8
        for (int k = 0; k < 64; ++k) av += s_x2[lv][k] * s_W[k * 32 + j5];
        xw[v * 32 + j5] = av;
    }
}

// GCN gather (CSR-ordered srcp/gwp, sequential) + relu + global pool
__global__ __launch_bounds__(256) void gcn_pool(
    const float* __restrict__ xw, const int* __restrict__ off,
    const int* __restrict__ srcp, const float* __restrict__ gwp,
    const float* __restrict__ gw, const float* __restrict__ gb,
    const int* __restrict__ seg, float* __restrict__ out)
{
    __shared__ float s_gb[32];
    const int t = threadIdx.x;
    if (t < 32) s_gb[t] = gb[t];
    __syncthreads();
    const int v = blockIdx.x * 8 + (t >> 5);
    const int c = t & 31;
    const int o0 = off[v], o1 = off[v + 1];
    float s = gw[E_EDGES + v] * xw[v * 32 + c];   // self loop
    for (int j = o0; j < o1; ++j)
        s += gwp[j] * xw[srcp[j] * 32 + c];
    const float val = fmaxf(s + s_gb[c], 0.f);
    atomicAdd(&out[seg[v] * 32 + c], val);
}

extern "C" void kernel_launch(void* const* d_in, const int* in_sizes, int n_in,
                              void* d_out, int out_size, void* d_ws, size_t ws_size,
                              hipStream_t stream)
{
    const float* x       = (const float*)d_in[0];
    const float* e       = (const float*)d_in[1];
    const int*   src     = (const int*)d_in[2];
    const int*   tgt     = (const int*)d_in[3];
    const int*   seg     = (const int*)d_in[4];
    const float* gcn_w   = (const float*)d_in[7];
    const float* e1_w0   = (const float*)d_in[8];
    const float* e1_b0   = (const float*)d_in[9];
    const float* e1_w1   = (const float*)d_in[10];
    const float* e1_b1   = (const float*)d_in[11];
    const float* e1_wk   = (const float*)d_in[12];
    const float* e1_bk   = (const float*)d_in[13];
    const float* e1_root = (const float*)d_in[14];
    const float* e1_bias = (const float*)d_in[15];
    const float* e2_w0   = (const float*)d_in[16];
    const float* e2_b0   = (const float*)d_in[17];
    const float* e2_w1   = (const float*)d_in[18];
    const float* e2_b1   = (const float*)d_in[19];
    const float* e2_wk   = (const float*)d_in[20];
    const float* e2_bk   = (const float*)d_in[21];
    const float* e2_root = (const float*)d_in[22];
    const float* e2_bias = (const float*)d_in[23];
    const float* gcn_W   = (const float*)d_in[24];
    const float* gcn_b   = (const float*)d_in[25];
    float* out = (float*)d_out;

    float*    ws    = (float*)d_ws;
    float*    x1    = ws;                                   // [N,32]
    float*    xw    = x1 + (size_t)N_NODES * 32;            // [N,32]
    unsigned* msg1  = (unsigned*)(xw + (size_t)N_NODES * 32);   // E*16 u32
    unsigned* msg2  = msg1 + (size_t)E_EDGES * 16;          // E*32 u32
    unsigned* h2buf = msg2 + (size_t)E_EDGES * 32;          // E*16 u32
    short*    wbt2  = (short*)(h2buf + (size_t)E_EDGES * 16);// 65536 bf16
    short*    wbt1  = wbt2 + 65536;                         // 8192 bf16
    short*    wt    = wbt1 + 8192;                          // 4096 bf16
    int*      deg   = (int*)(wt + 4096);                    // N
    int*      off   = deg + N_NODES;                        // N+1 (+pad)
    int*      cursor= off + N_NODES + 16;                   // N
    int*      srcp  = cursor + N_NODES;                     // E
    float*    gwp   = (float*)(srcp + E_EDGES);             // E

    hipMemsetAsync(deg, 0, N_NODES * sizeof(int), stream);
    hipMemsetAsync(out, 0, (size_t)out_size * sizeof(float), stream);

    prep<<<E_EDGES / 256, 256, 0, stream>>>(
        e2_wk, e2_bk, e1_wk, e1_bk,
        e1_w0, e1_b0, e1_w1, e1_b1, e2_w0, e2_b0, e2_w1, e2_b1,
        tgt, wbt2, wbt1, wt, deg);
    csr_scan<<<1, 1024, 0, stream>>>(deg, off, cursor);

    ecc1_fused<<<E_EDGES / 256, 256, 0, stream>>>(x, e, src, tgt, gcn_w,
        wt, wbt1, cursor, srcp, gwp, msg1, h2buf);
    gather1<<<N_NODES / 16, 256, 0, stream>>>(msg1, off, x, e1_root, e1_bias, x1);
    ecc2_mfma<<<E_EDGES / 128, 256, 0, stream>>>(x1, srcp, h2buf, wbt2, msg2);
    gather2<<<N_NODES / 32, 256, 0, stream>>>(msg2, off, x1,
        e2_root, e2_bias, gcn_W, xw);
    gcn_pool<<<N_NODES / 8, 256, 0, stream>>>(xw, off, srcp, gwp,
        gcn_w, gcn_b, seg, out);
}